// Round 8
// baseline (226.979 us; speedup 1.0000x reference)
//
#include <hip/hip_runtime.h>
#include <hip/hip_fp16.h>

// ---------------------------------------------------------------------------
// 3-layer GCN, CSR-gather, fp16 dataflow + MFMA GEMM, fused pipeline R23b:
// EXACT R21 (211.6us) structure + ONE change: scattered gather row loads use
// __builtin_nontemporal_load (MUBUF nt) -> bypass L1. Theory: gather is
// concurrency-capped by the per-CU L1 miss queue (every row load = 4-line L1
// miss, ~0% L1 hit on 12.8MB set; effective ~15 loads in flight/CU vs ~200
// resident). L2/L3 queues are deeper -> more misses in flight.
// (R23b: fixed compile error — builtin needs a native vector type, so the
// load goes through v4f (ext_vector_type) instead of HIP_vector_type float4.)
//   memset:       cnt8 = 0
//   count+wcast:  8-BANK cnt histogram (XCD-local atomics, R19) || Wt cast
//   scan x2:      row_ptr (deg = sum of banks) + dis + per-bank base8
//   gemm1+bin:    HWS1 = half(dis*(x@W1)) || CSR bin via base8+rank
//   gather+gemm2: h1 = relu(dis*S HWS1 + b1) -> LDS -> HWS2 = half(dis*(h1@W2))
//   gather+gemv:  hw3s = dis * dot(relu(dis*S HWS2 + b2), W3)
//   gather3:      out = relu(dis*S hw3s + b3)
// Lessons: R18 row-sort FAILED (no locality in random edges). R19 per-edge
// dis[s] loads FAILED (+requests on latency-bound loop). R20 depth-8 FAILED
// (occupancy trade cancels MLP). R22 degree-sort FAILED (perm indirection +
// histogram cost >= divergence win). Banked count: neutral-to-positive.
// VGPR<64 hot kernels; never force min-waves.
// ---------------------------------------------------------------------------

typedef _Float16 v8h __attribute__((ext_vector_type(8)));
typedef float v4f __attribute__((ext_vector_type(4)));

// nontemporal 16B load through a native vector type (builtin requirement)
__device__ __forceinline__ float4 ntload16(const float4* p) {
    v4f v = __builtin_nontemporal_load((const v4f*)p);
    return *(float4*)&v;
}

// fused: 8-bank edge count + rank record (blocks [0,BE)) + weight cast.
__global__ __launch_bounds__(256) void k_count_wcast(const int* __restrict__ dst,
                                                     int* __restrict__ cnt8,
                                                     int* __restrict__ rank, int nE,
                                                     int BE, int nN,
                                                     const float* __restrict__ W1,
                                                     const float* __restrict__ W2,
                                                     __half* __restrict__ Wt1,
                                                     __half* __restrict__ Wt2) {
    int b = blockIdx.x;
    if (b < BE) {
        int e = b * 256 + threadIdx.x;
        if (e < nE) {
            int bank = b & 7;
            rank[e] = atomicAdd(&cnt8[bank * nN + dst[e]], 1);
        }
    } else {
        int i = (b - BE) * 256 + threadIdx.x;   // 0..16383
        int k = i >> 7, c = i & 127;
        Wt1[c * 128 + k] = __float2half(W1[i]);
        Wt2[c * 128 + k] = __float2half(W2[i]);
    }
}

// scan stage 1: deg = sum of 8 banks, fused dis = rsqrt(deg+1)
__global__ __launch_bounds__(256) void k_scan_blk(const int* __restrict__ cnt8,
                                                  float* __restrict__ dis,
                                                  int* __restrict__ excl,
                                                  int* __restrict__ blk_sum, int nN) {
    __shared__ int sm[256];
    const int t = threadIdx.x;
    int i = blockIdx.x * 256 + t;
    int v = 0;
    if (i < nN) {
#pragma unroll
        for (int b = 0; b < 8; ++b) v += cnt8[b * nN + i];
        dis[i] = rsqrtf((float)v + 1.0f);
    }
    sm[t] = v;
    __syncthreads();
#pragma unroll
    for (int off = 1; off < 256; off <<= 1) {
        int x = (t >= off) ? sm[t - off] : 0;
        __syncthreads();
        sm[t] += x;
        __syncthreads();
    }
    if (i < nN) excl[i] = sm[t] - v;
    if (t == 255) blk_sum[blockIdx.x] = sm[255];
}

// stage 2+3 fused + per-bank base emission:
// base8[i*8+b] = row_ptr[i] + sum_{b'<b} cnt8[b'][i]
__global__ __launch_bounds__(256) void k_scan_add(const int* __restrict__ excl,
                                                  const int* __restrict__ blk_sum,
                                                  const int* __restrict__ cnt8,
                                                  int* __restrict__ row_ptr,
                                                  int* __restrict__ base8,
                                                  int nN, int nB) {
    __shared__ int sm[256];
    const int t = threadIdx.x;
    int v = (t < nB) ? blk_sum[t] : 0;
    sm[t] = v;
    __syncthreads();
#pragma unroll
    for (int off = 1; off < 256; off <<= 1) {
        int x = (t >= off) ? sm[t - off] : 0;
        __syncthreads();
        sm[t] += x;
        __syncthreads();
    }
    int i = blockIdx.x * 256 + t;
    if (i < nN) {
        int b = i >> 8;
        int rp = excl[i] + sm[b] - blk_sum[b];
        row_ptr[i] = rp;
        int off = rp;
#pragma unroll
        for (int bk = 0; bk < 8; ++bk) {
            base8[i * 8 + bk] = off;
            off += cnt8[bk * nN + i];
        }
    }
    if (i == 0) row_ptr[nN] = sm[255];
}

// add 8 halves (packed in a float4) into acc[8] (fp32)
__device__ __forceinline__ void add8(float acc[8], float4 r) {
    __half2* hp = (__half2*)&r;
#pragma unroll
    for (int k = 0; k < 4; ++k) {
        float2 f = __half22float2(hp[k]);
        acc[2 * k] += f.x;
        acc[2 * k + 1] += f.y;
    }
}

// QUARTER-WAVE gather: 16 lanes per node row, 16B (8 halves) per lane.
// Scattered row loads are NONTEMPORAL (nt): bypass L1 (0% hit on 12.8MB set)
// so in-flight miss count isn't capped by the L1 miss queue.
__device__ __forceinline__ void gather_row16(const float4* __restrict__ Hv,
                                             const int* __restrict__ row_ptr,
                                             const int* __restrict__ src_csr,
                                             int g, int f8, float acc[8]) {
    int beg = row_ptr[g], end = row_ptr[g + 1];
#pragma unroll
    for (int k = 0; k < 8; ++k) acc[k] = 0.f;
    add8(acc, Hv[(size_t)g * 16 + f8]);   // self term (block-local rows: keep L1)
    int e = beg;
    for (; e + 4 <= end; e += 4) {        // 4-deep batch: r[4]x4 = 16 VGPRs
        int s[4];
#pragma unroll
        for (int j = 0; j < 4; ++j) s[j] = src_csr[e + j];
        float4 r[4];
#pragma unroll
        for (int j = 0; j < 4; ++j)
            r[j] = ntload16(&Hv[(size_t)s[j] * 16 + f8]);
#pragma unroll
        for (int j = 0; j < 4; ++j) add8(acc, r[j]);
    }
    for (; e < end; ++e)
        add8(acc, ntload16(&Hv[(size_t)src_csr[e] * 16 + f8]));
}

// FUSED dispatch: blocks [0,BG) = layer-1 MFMA GEMM; blocks >=BG = CSR bin.
__global__ __launch_bounds__(256) void k_gemm_bin(const float* __restrict__ X32,
                                                  const __half* __restrict__ Wt,
                                                  const float* __restrict__ dis,
                                                  __half* __restrict__ HWS,
                                                  int nrows, int BG,
                                                  const int* __restrict__ src,
                                                  const int* __restrict__ dst,
                                                  const int* __restrict__ rank,
                                                  const int* __restrict__ base8,
                                                  int* __restrict__ src_csr, int nE) {
    __shared__ __half xs[64 * 136];
    if (blockIdx.x >= BG) {
        // --- binning path (no atomics) ---
        int eb = blockIdx.x - BG;
        int e = eb * 256 + threadIdx.x;
        if (e < nE) {
            int d = dst[e];
            int bank = eb & 7;
            src_csr[base8[d * 8 + bank] + rank[e]] = src[e];
        }
        return;
    }

    // --- GEMM path ---
    const int t = threadIdx.x;
    const int row0 = blockIdx.x * 64;

#pragma unroll
    for (int i = 0; i < 8; ++i) {
        int f = t + i * 256;
        int r = f >> 5, k4 = f & 31;
        int gr = row0 + r;
        float4 v = make_float4(0.f, 0.f, 0.f, 0.f);
        if (gr < nrows) v = ((const float4*)X32)[(size_t)gr * 32 + k4];
        __half2 h01 = __float22half2_rn(make_float2(v.x, v.y));
        __half2 h23 = __float22half2_rn(make_float2(v.z, v.w));
        float2 packed;
        *(__half2*)&packed.x = h01;
        *(__half2*)&packed.y = h23;
        *(float2*)&xs[r * 136 + k4 * 4] = packed;
    }
    __syncthreads();

    const int w = t >> 6;
    const int l = t & 63;
    const int mrow = l & 15;
    const int kq = l >> 4;

    v8h a[4];
#pragma unroll
    for (int kk = 0; kk < 4; ++kk)
        a[kk] = *(const v8h*)&xs[(w * 16 + mrow) * 136 + kk * 32 + kq * 8];

    v4f acc[8];
#pragma unroll
    for (int c = 0; c < 8; ++c) acc[c] = (v4f){0.f, 0.f, 0.f, 0.f};

#pragma unroll
    for (int kk = 0; kk < 4; ++kk) {
#pragma unroll
        for (int c = 0; c < 8; ++c) {
            v8h b = *(const v8h*)&Wt[(size_t)(c * 16 + mrow) * 128 + kk * 32 + kq * 8];
            acc[c] = __builtin_amdgcn_mfma_f32_16x16x32_f16(a[kk], b, acc[c], 0, 0, 0);
        }
    }

    float dn[4];
#pragma unroll
    for (int r = 0; r < 4; ++r) {
        int grow = row0 + w * 16 + kq * 4 + r;
        dn[r] = (grow < nrows) ? dis[grow] : 0.f;
    }
#pragma unroll
    for (int c = 0; c < 8; ++c) {
#pragma unroll
        for (int r = 0; r < 4; ++r) {
            int grow = row0 + w * 16 + kq * 4 + r;
            if (grow < nrows)
                HWS[(size_t)grow * 128 + c * 16 + mrow] =
                    __float2half(acc[c][r] * dn[r]);
        }
    }
}

// FUSED layer-1 gather + layer-2 GEMM, 512 threads.
__global__ __launch_bounds__(512) void k_gather_gemm(const __half* __restrict__ HWS1,
                                                     const int* __restrict__ row_ptr,
                                                     const int* __restrict__ src_csr,
                                                     const float* __restrict__ dis,
                                                     const float* __restrict__ bias,
                                                     const __half* __restrict__ Wt,
                                                     __half* __restrict__ HWS2,
                                                     int nN) {
    __shared__ __half xs[64 * 136];
    __shared__ int q;
    const int t = threadIdx.x;
    const int row0 = blockIdx.x * 64;
    const int l = t & 63;
    const int f8 = t & 15;            // lane within quarter-wave
    const int qbase = l & 48;         // base lane of this quarter in the wave
    const float4* Hv = (const float4*)HWS1;

    float bv[8];
    *(float4*)&bv[0] = ((const float4*)bias)[f8 * 2];
    *(float4*)&bv[4] = ((const float4*)bias)[f8 * 2 + 1];

    if (t == 0) q = 0;
    __syncthreads();

    for (;;) {
        int lr = 0;
        if (f8 == 0) lr = atomicAdd(&q, 1);
        lr = __shfl(lr, qbase, 64);
        if (lr >= 64) break;
        int g = row0 + lr;
        float acc[8];
        __half2 h[4];
        if (g < nN) {
            gather_row16(Hv, row_ptr, src_csr, g, f8, acc);
            float dn = dis[g];
#pragma unroll
            for (int k = 0; k < 4; ++k)
                h[k] = __float22half2_rn(make_float2(
                    fmaxf(acc[2 * k] * dn + bv[2 * k], 0.f),
                    fmaxf(acc[2 * k + 1] * dn + bv[2 * k + 1], 0.f)));
        } else {
#pragma unroll
            for (int k = 0; k < 4; ++k) h[k] = __float2half2_rn(0.f);
        }
        *(float4*)&xs[lr * 136 + f8 * 8] = *(float4*)h;   // 16B ds_write_b128
    }
    __syncthreads();

    const int w = t >> 6;        // wave 0..7
    const int mrow = l & 15;
    const int kq = l >> 4;
    const int rgrp = (w & 3) * 16;   // row group
    const int cgrp = (w >> 2) * 4;   // col-tile group (4 tiles of 16)

    v8h a[4];
#pragma unroll
    for (int kk = 0; kk < 4; ++kk)
        a[kk] = *(const v8h*)&xs[(rgrp + mrow) * 136 + kk * 32 + kq * 8];

    v4f acc[4];
#pragma unroll
    for (int c = 0; c < 4; ++c) acc[c] = (v4f){0.f, 0.f, 0.f, 0.f};

#pragma unroll
    for (int kk = 0; kk < 4; ++kk) {
#pragma unroll
        for (int c = 0; c < 4; ++c) {
            v8h b = *(const v8h*)&Wt[(size_t)((cgrp + c) * 16 + mrow) * 128 + kk * 32 + kq * 8];
            acc[c] = __builtin_amdgcn_mfma_f32_16x16x32_f16(a[kk], b, acc[c], 0, 0, 0);
        }
    }

    float dn4[4];
#pragma unroll
    for (int r = 0; r < 4; ++r) {
        int grow = row0 + rgrp + kq * 4 + r;
        dn4[r] = (grow < nN) ? dis[grow] : 0.f;
    }
#pragma unroll
    for (int c = 0; c < 4; ++c) {
#pragma unroll
        for (int r = 0; r < 4; ++r) {
            int grow = row0 + rgrp + kq * 4 + r;
            if (grow < nN)
                HWS2[(size_t)grow * 128 + (cgrp + c) * 16 + mrow] =
                    __float2half(acc[c][r] * dn4[r]);
        }
    }
}

// FUSED layer-2 gather + layer-3 gemv (quarter-wave gather, 16 nodes/block):
//   hw3s[g] = dis[g] * dot(relu(dis[g]*S HWS2 + b2), W3)
__global__ __launch_bounds__(256) void k_gather_gemv(const __half* __restrict__ HWS2,
                                                     const int* __restrict__ row_ptr,
                                                     const int* __restrict__ src_csr,
                                                     const float* __restrict__ dis,
                                                     const float* __restrict__ bias,
                                                     const float* __restrict__ W3,
                                                     float* __restrict__ hw3s, int nN) {
    int g = blockIdx.x * 16 + (threadIdx.x >> 4);
    if (g >= nN) return;
    int f8 = threadIdx.x & 15;
    float acc[8];
    gather_row16((const float4*)HWS2, row_ptr, src_csr, g, f8, acc);
    float dn = dis[g];
    float bv[8], w3[8];
    *(float4*)&bv[0] = ((const float4*)bias)[f8 * 2];
    *(float4*)&bv[4] = ((const float4*)bias)[f8 * 2 + 1];
    *(float4*)&w3[0] = ((const float4*)W3)[f8 * 2];
    *(float4*)&w3[4] = ((const float4*)W3)[f8 * 2 + 1];
    float sum = 0.f;
#pragma unroll
    for (int k = 0; k < 8; ++k)
        sum += fmaxf(acc[k] * dn + bv[k], 0.f) * w3[k];
#pragma unroll
    for (int off = 8; off > 0; off >>= 1) sum += __shfl_down(sum, off, 16);
    if (f8 == 0) hw3s[g] = sum * dn;
}

// scalar pull-aggregation + final relu -> d_out
__global__ __launch_bounds__(256) void k_gather3(const float* __restrict__ hw3s,
                                                 const int* __restrict__ row_ptr,
                                                 const int* __restrict__ src_csr,
                                                 const float* __restrict__ dis,
                                                 const float* __restrict__ b3,
                                                 float* __restrict__ out, int nN) {
    int i = blockIdx.x * 256 + threadIdx.x;
    if (i >= nN) return;
    float acc = hw3s[i];
    int beg = row_ptr[i], end = row_ptr[i + 1];
    for (int e = beg; e < end; ++e) acc += hw3s[src_csr[e]];
    out[i] = fmaxf(acc * dis[i] + b3[0], 0.f);
}

extern "C" void kernel_launch(void* const* d_in, const int* in_sizes, int n_in,
                              void* d_out, int out_size, void* d_ws, size_t ws_size,
                              hipStream_t stream) {
    const float* x  = (const float*)d_in[0];
    const int*   ei = (const int*)d_in[1];
    const float* W1 = (const float*)d_in[2];
    const float* b1 = (const float*)d_in[3];
    const float* W2 = (const float*)d_in[4];
    const float* b2 = (const float*)d_in[5];
    const float* W3 = (const float*)d_in[6];
    const float* b3 = (const float*)d_in[7];

    const int nN = in_sizes[0] / 128;
    const int nE = in_sizes[1] / 2;
    const int* src = ei;
    const int* dst = ei + nE;

    const int nB = (nN + 255) / 256;   // scan blocks (<=256)

    // workspace layout
    char* p = (char*)d_ws;
    int*    cnt8     = (int*)p;           p += (size_t)nN * 8 * 4;
    int*    base8    = (int*)p;           p += (size_t)nN * 8 * 4;
    int*    excl     = (int*)p;           p += (size_t)nN * 4;
    int*    blk_sum  = (int*)p;           p += (size_t)(nB + 1) * 4;
    int*    row_ptr  = (int*)p;           p += (size_t)(nN + 1) * 4;
    int*    rank     = (int*)p;           p += (size_t)nE * 4;
    int*    src_csr  = (int*)p;           p += (size_t)nE * 4;
    float*  dis      = (float*)p;         p += (size_t)nN * 4;
    float*  hw3s     = (float*)p;         p += (size_t)nN * 4;
    p = (char*)(((uintptr_t)p + 255) & ~(uintptr_t)255);
    __half* Wt1      = (__half*)p;        p += (size_t)128 * 128 * 2;
    __half* Wt2      = (__half*)p;        p += (size_t)128 * 128 * 2;
    __half* bufA     = (__half*)p;        p += (size_t)nN * 128 * 2;  // HWS1
    p = (char*)(((uintptr_t)p + 255) & ~(uintptr_t)255);
    __half* bufB     = (__half*)p;        p += (size_t)nN * 128 * 2;  // HWS2

    const int BE  = (nE + 255) / 256;            // 2344
    const int BN  = (nN + 255) / 256;            // 196
    const int BG  = (nN + 63) / 64;              // 782
    const int BGV = (nN + 15) / 16;              // 3125

    // --- CSR build + norms + weight cast (banked count) ---
    hipMemsetAsync(cnt8, 0, (size_t)nN * 8 * sizeof(int), stream);
    k_count_wcast<<<BE + 64, 256, 0, stream>>>(dst, cnt8, rank, nE, BE, nN,
                                               W1, W2, Wt1, Wt2);
    k_scan_blk<<<nB, 256, 0, stream>>>(cnt8, dis, excl, blk_sum, nN);
    k_scan_add<<<nB, 256, 0, stream>>>(excl, blk_sum, cnt8, row_ptr, base8, nN, nB);

    // --- layer-1 GEMM (blocks [0,BG)) overlapped with atomic-free binning ---
    k_gemm_bin<<<BG + BE, 256, 0, stream>>>(x, Wt1, dis, bufA, nN, BG,
                                            src, dst, rank, base8, src_csr, nE);

    // --- fused layer-1 gather + layer-2 GEMM: HWS1 -> HWS2 (512 thr) ---
    k_gather_gemm<<<BG, 512, 0, stream>>>(bufA, row_ptr, src_csr, dis, b1, Wt2,
                                          bufB, nN);

    // --- fused layer-2 gather + layer-3 gemv: HWS2 -> hw3s ---
    k_gather_gemv<<<BGV, 256, 0, stream>>>(bufB, row_ptr, src_csr, dis, b2, W3,
                                           hw3s, nN);

    // --- layer-3 scalar gather -> d_out ---
    k_gather3<<<BN, 256, 0, stream>>>(hw3s, row_ptr, src_csr, dis, b3,
                                      (float*)d_out, nN);
}

// Round 9
// 211.039 us; speedup vs baseline: 1.0755x; 1.0755x over previous
//
#include <hip/hip_runtime.h>
#include <hip/hip_fp16.h>

// ---------------------------------------------------------------------------
// 3-layer GCN, CSR-gather, fp16 dataflow + MFMA GEMM, fused pipeline R24:
// R21 (211.6us) base + PIPELINED GATHER:
//   (a) block's CSR index range staged in LDS (contiguous slice of src_csr,
//       coalesced preload) -> index fetch leaves the global-latency chain;
//   (b) double-buffered depth-4 row loads: next batch ISSUED before current
//       batch consumed -> compiler emits counted vmcnt(4), 2 batches in
//       flight per quarter-wave. Self-term issued first, consumed last.
// Theory: R23b's rate measurement (~208cy per 4-edge batch slot) matches the
// serial idx-load(~200cy)->row-load(~600cy) chain; staging+dbuf cuts it to
// ~1 row-latency per 2 batches.
//   memset:       cnt8 = 0
//   count+wcast:  8-BANK cnt histogram (XCD-local atomics, R19) || Wt cast
//   scan x2:      row_ptr (deg = sum of banks) + dis + per-bank base8
//   gemm1+bin:    HWS1 = half(dis*(x@W1)) || CSR bin via base8+rank
//   gather+gemm2: h1 = relu(dis*S HWS1 + b1) -> LDS -> HWS2 = half(dis*(h1@W2))
//   gather+gemv:  hw3s = dis * dot(relu(dis*S HWS2 + b2), W3)
//   gather3:      out = relu(dis*S hw3s + b3)
// Lessons: R18 row-sort FAILED. R19 per-edge dis[s] FAILED. R20 depth-8
// FAILED (occupancy trade; chain unbroken). R22 degree-sort FAILED. R23b
// nt/L1-bypass FAILED (+7us: lost L1 reuse, cap is not L1 miss queue).
// Banked count neutral-to-positive. VGPR<64 hot kernels; never force
// min-waves.
// ---------------------------------------------------------------------------

typedef _Float16 v8h __attribute__((ext_vector_type(8)));
typedef float v4f __attribute__((ext_vector_type(4)));

// fused: 8-bank edge count + rank record (blocks [0,BE)) + weight cast.
__global__ __launch_bounds__(256) void k_count_wcast(const int* __restrict__ dst,
                                                     int* __restrict__ cnt8,
                                                     int* __restrict__ rank, int nE,
                                                     int BE, int nN,
                                                     const float* __restrict__ W1,
                                                     const float* __restrict__ W2,
                                                     __half* __restrict__ Wt1,
                                                     __half* __restrict__ Wt2) {
    int b = blockIdx.x;
    if (b < BE) {
        int e = b * 256 + threadIdx.x;
        if (e < nE) {
            int bank = b & 7;
            rank[e] = atomicAdd(&cnt8[bank * nN + dst[e]], 1);
        }
    } else {
        int i = (b - BE) * 256 + threadIdx.x;   // 0..16383
        int k = i >> 7, c = i & 127;
        Wt1[c * 128 + k] = __float2half(W1[i]);
        Wt2[c * 128 + k] = __float2half(W2[i]);
    }
}

// scan stage 1: deg = sum of 8 banks, fused dis = rsqrt(deg+1)
__global__ __launch_bounds__(256) void k_scan_blk(const int* __restrict__ cnt8,
                                                  float* __restrict__ dis,
                                                  int* __restrict__ excl,
                                                  int* __restrict__ blk_sum, int nN) {
    __shared__ int sm[256];
    const int t = threadIdx.x;
    int i = blockIdx.x * 256 + t;
    int v = 0;
    if (i < nN) {
#pragma unroll
        for (int b = 0; b < 8; ++b) v += cnt8[b * nN + i];
        dis[i] = rsqrtf((float)v + 1.0f);
    }
    sm[t] = v;
    __syncthreads();
#pragma unroll
    for (int off = 1; off < 256; off <<= 1) {
        int x = (t >= off) ? sm[t - off] : 0;
        __syncthreads();
        sm[t] += x;
        __syncthreads();
    }
    if (i < nN) excl[i] = sm[t] - v;
    if (t == 255) blk_sum[blockIdx.x] = sm[255];
}

// stage 2+3 fused + per-bank base emission:
// base8[i*8+b] = row_ptr[i] + sum_{b'<b} cnt8[b'][i]
__global__ __launch_bounds__(256) void k_scan_add(const int* __restrict__ excl,
                                                  const int* __restrict__ blk_sum,
                                                  const int* __restrict__ cnt8,
                                                  int* __restrict__ row_ptr,
                                                  int* __restrict__ base8,
                                                  int nN, int nB) {
    __shared__ int sm[256];
    const int t = threadIdx.x;
    int v = (t < nB) ? blk_sum[t] : 0;
    sm[t] = v;
    __syncthreads();
#pragma unroll
    for (int off = 1; off < 256; off <<= 1) {
        int x = (t >= off) ? sm[t - off] : 0;
        __syncthreads();
        sm[t] += x;
        __syncthreads();
    }
    int i = blockIdx.x * 256 + t;
    if (i < nN) {
        int b = i >> 8;
        int rp = excl[i] + sm[b] - blk_sum[b];
        row_ptr[i] = rp;
        int off = rp;
#pragma unroll
        for (int bk = 0; bk < 8; ++bk) {
            base8[i * 8 + bk] = off;
            off += cnt8[bk * nN + i];
        }
    }
    if (i == 0) row_ptr[nN] = sm[255];
}

// add 8 halves (packed in a float4) into acc[8] (fp32)
__device__ __forceinline__ void add8(float acc[8], float4 r) {
    __half2* hp = (__half2*)&r;
#pragma unroll
    for (int k = 0; k < 4; ++k) {
        float2 f = __half22float2(hp[k]);
        acc[2 * k] += f.x;
        acc[2 * k + 1] += f.y;
    }
}

// PIPELINED quarter-wave gather: 16 lanes x 16B per node row. Indices come
// from idx[] (LDS-staged slice or global fallback). Depth-4 double buffer:
// batch B's row loads are ISSUED before batch A is consumed -> compiler
// emits counted vmcnt waits, 2 batches (8 rows) in flight. Self row issued
// first, consumed last (never stalls the pipeline head).
__device__ __forceinline__ void gather_pipe16(const float4* __restrict__ Hv,
                                              const int* idx, int beg, int end,
                                              int g, int f8, float acc[8]) {
#pragma unroll
    for (int k = 0; k < 8; ++k) acc[k] = 0.f;
    float4 selfr = Hv[(size_t)g * 16 + f8];   // issued now, consumed at end
    int n = end - beg;
    if (n > 0) {
        float4 rA[4];
        int e = beg;
        int cA = n < 4 ? n : 4;
#pragma unroll
        for (int j = 0; j < 4; ++j) {
            int jj = j < cA ? j : cA - 1;     // clamped duplicate on tail
            rA[j] = Hv[(size_t)idx[e + jj] * 16 + f8];
        }
        e += cA;
        while (e < end) {
            int rem = end - e;
            int cB = rem < 4 ? rem : 4;
            float4 rB[4];
#pragma unroll
            for (int j = 0; j < 4; ++j) {
                int jj = j < cB ? j : cB - 1;
                rB[j] = Hv[(size_t)idx[e + jj] * 16 + f8];
            }
            // consume A AFTER issuing B -> vmcnt(4), B stays in flight
#pragma unroll
            for (int j = 0; j < 4; ++j)
                if (j < cA) add8(acc, rA[j]);
#pragma unroll
            for (int j = 0; j < 4; ++j) rA[j] = rB[j];
            cA = cB;
            e += cB;
        }
#pragma unroll
        for (int j = 0; j < 4; ++j)
            if (j < cA) add8(acc, rA[j]);
    }
    add8(acc, selfr);
}

// FUSED dispatch: blocks [0,BG) = layer-1 MFMA GEMM; blocks >=BG = CSR bin.
__global__ __launch_bounds__(256) void k_gemm_bin(const float* __restrict__ X32,
                                                  const __half* __restrict__ Wt,
                                                  const float* __restrict__ dis,
                                                  __half* __restrict__ HWS,
                                                  int nrows, int BG,
                                                  const int* __restrict__ src,
                                                  const int* __restrict__ dst,
                                                  const int* __restrict__ rank,
                                                  const int* __restrict__ base8,
                                                  int* __restrict__ src_csr, int nE) {
    __shared__ __half xs[64 * 136];
    if (blockIdx.x >= BG) {
        // --- binning path (no atomics) ---
        int eb = blockIdx.x - BG;
        int e = eb * 256 + threadIdx.x;
        if (e < nE) {
            int d = dst[e];
            int bank = eb & 7;
            src_csr[base8[d * 8 + bank] + rank[e]] = src[e];
        }
        return;
    }

    // --- GEMM path ---
    const int t = threadIdx.x;
    const int row0 = blockIdx.x * 64;

#pragma unroll
    for (int i = 0; i < 8; ++i) {
        int f = t + i * 256;
        int r = f >> 5, k4 = f & 31;
        int gr = row0 + r;
        float4 v = make_float4(0.f, 0.f, 0.f, 0.f);
        if (gr < nrows) v = ((const float4*)X32)[(size_t)gr * 32 + k4];
        __half2 h01 = __float22half2_rn(make_float2(v.x, v.y));
        __half2 h23 = __float22half2_rn(make_float2(v.z, v.w));
        float2 packed;
        *(__half2*)&packed.x = h01;
        *(__half2*)&packed.y = h23;
        *(float2*)&xs[r * 136 + k4 * 4] = packed;
    }
    __syncthreads();

    const int w = t >> 6;
    const int l = t & 63;
    const int mrow = l & 15;
    const int kq = l >> 4;

    v8h a[4];
#pragma unroll
    for (int kk = 0; kk < 4; ++kk)
        a[kk] = *(const v8h*)&xs[(w * 16 + mrow) * 136 + kk * 32 + kq * 8];

    v4f acc[8];
#pragma unroll
    for (int c = 0; c < 8; ++c) acc[c] = (v4f){0.f, 0.f, 0.f, 0.f};

#pragma unroll
    for (int kk = 0; kk < 4; ++kk) {
#pragma unroll
        for (int c = 0; c < 8; ++c) {
            v8h b = *(const v8h*)&Wt[(size_t)(c * 16 + mrow) * 128 + kk * 32 + kq * 8];
            acc[c] = __builtin_amdgcn_mfma_f32_16x16x32_f16(a[kk], b, acc[c], 0, 0, 0);
        }
    }

    float dn[4];
#pragma unroll
    for (int r = 0; r < 4; ++r) {
        int grow = row0 + w * 16 + kq * 4 + r;
        dn[r] = (grow < nrows) ? dis[grow] : 0.f;
    }
#pragma unroll
    for (int c = 0; c < 8; ++c) {
#pragma unroll
        for (int r = 0; r < 4; ++r) {
            int grow = row0 + w * 16 + kq * 4 + r;
            if (grow < nrows)
                HWS[(size_t)grow * 128 + c * 16 + mrow] =
                    __float2half(acc[c][r] * dn[r]);
        }
    }
}

// FUSED layer-1 gather + layer-2 GEMM, 512 threads.
//   phase 0: cooperative LDS stage of the block's CSR index slice
//            (src_csr[row_ptr[row0] .. row_ptr[row0+64]) is CONTIGUOUS).
//   phase 1: 32 quarter-waves pull node slots from an LDS queue; pipelined
//            depth-4 dbuf gather per row.
//   phase 2: 8 MFMA waves.
__global__ __launch_bounds__(512) void k_gather_gemm(const __half* __restrict__ HWS1,
                                                     const int* __restrict__ row_ptr,
                                                     const int* __restrict__ src_csr,
                                                     const float* __restrict__ dis,
                                                     const float* __restrict__ bias,
                                                     const __half* __restrict__ Wt,
                                                     __half* __restrict__ HWS2,
                                                     int nN) {
    __shared__ __half xs[64 * 136];
    __shared__ int idxs[2048];
    __shared__ int q;
    const int t = threadIdx.x;
    const int row0 = blockIdx.x * 64;
    const int l = t & 63;
    const int f8 = t & 15;            // lane within quarter-wave
    const int qbase = l & 48;         // base lane of this quarter in the wave
    const float4* Hv = (const float4*)HWS1;

    float bv[8];
    *(float4*)&bv[0] = ((const float4*)bias)[f8 * 2];
    *(float4*)&bv[4] = ((const float4*)bias)[f8 * 2 + 1];

    // --- phase 0: stage block's index slice (coalesced) ---
    int rhi = row0 + 64; if (rhi > nN) rhi = nN;
    const int ebeg = row_ptr[row0];
    const int eend = row_ptr[rhi];
    int ncap = eend - ebeg;
    if (ncap > 2048) ncap = 2048;
    for (int i = t; i < ncap; i += 512) idxs[i] = src_csr[ebeg + i];

    if (t == 0) q = 0;
    __syncthreads();

    for (;;) {
        int lr = 0;
        if (f8 == 0) lr = atomicAdd(&q, 1);
        lr = __shfl(lr, qbase, 64);
        if (lr >= 64) break;
        int g = row0 + lr;
        float acc[8];
        __half2 h[4];
        if (g < nN) {
            int gb = row_ptr[g], ge = row_ptr[g + 1];
            if (ge - ebeg <= ncap)
                gather_pipe16(Hv, idxs, gb - ebeg, ge - ebeg, g, f8, acc);
            else   // overflow fallback (degenerate blocks only)
                gather_pipe16(Hv, src_csr, gb, ge, g, f8, acc);
            float dn = dis[g];
#pragma unroll
            for (int k = 0; k < 4; ++k)
                h[k] = __float22half2_rn(make_float2(
                    fmaxf(acc[2 * k] * dn + bv[2 * k], 0.f),
                    fmaxf(acc[2 * k + 1] * dn + bv[2 * k + 1], 0.f)));
        } else {
#pragma unroll
            for (int k = 0; k < 4; ++k) h[k] = __float2half2_rn(0.f);
        }
        *(float4*)&xs[lr * 136 + f8 * 8] = *(float4*)h;   // 16B ds_write_b128
    }
    __syncthreads();

    const int w = t >> 6;        // wave 0..7
    const int mrow = l & 15;
    const int kq = l >> 4;
    const int rgrp = (w & 3) * 16;   // row group
    const int cgrp = (w >> 2) * 4;   // col-tile group (4 tiles of 16)

    v8h a[4];
#pragma unroll
    for (int kk = 0; kk < 4; ++kk)
        a[kk] = *(const v8h*)&xs[(rgrp + mrow) * 136 + kk * 32 + kq * 8];

    v4f acc[4];
#pragma unroll
    for (int c = 0; c < 4; ++c) acc[c] = (v4f){0.f, 0.f, 0.f, 0.f};

#pragma unroll
    for (int kk = 0; kk < 4; ++kk) {
#pragma unroll
        for (int c = 0; c < 4; ++c) {
            v8h b = *(const v8h*)&Wt[(size_t)((cgrp + c) * 16 + mrow) * 128 + kk * 32 + kq * 8];
            acc[c] = __builtin_amdgcn_mfma_f32_16x16x32_f16(a[kk], b, acc[c], 0, 0, 0);
        }
    }

    float dn4[4];
#pragma unroll
    for (int r = 0; r < 4; ++r) {
        int grow = row0 + rgrp + kq * 4 + r;
        dn4[r] = (grow < nN) ? dis[grow] : 0.f;
    }
#pragma unroll
    for (int c = 0; c < 4; ++c) {
#pragma unroll
        for (int r = 0; r < 4; ++r) {
            int grow = row0 + rgrp + kq * 4 + r;
            if (grow < nN)
                HWS2[(size_t)grow * 128 + (cgrp + c) * 16 + mrow] =
                    __float2half(acc[c][r] * dn4[r]);
        }
    }
}

// FUSED layer-2 gather + layer-3 gemv (16 nodes/block, LDS-staged indices,
// pipelined gather): hw3s[g] = dis[g] * dot(relu(dis[g]*S HWS2 + b2), W3)
__global__ __launch_bounds__(256) void k_gather_gemv(const __half* __restrict__ HWS2,
                                                     const int* __restrict__ row_ptr,
                                                     const int* __restrict__ src_csr,
                                                     const float* __restrict__ dis,
                                                     const float* __restrict__ bias,
                                                     const float* __restrict__ W3,
                                                     float* __restrict__ hw3s, int nN) {
    __shared__ int idxs[768];
    const int g0 = blockIdx.x * 16;
    int ghi = g0 + 16; if (ghi > nN) ghi = nN;
    const int ebeg = row_ptr[g0 < nN ? g0 : nN];
    const int eend = row_ptr[ghi];
    int ncap = eend - ebeg;
    if (ncap > 768) ncap = 768;
    for (int i = threadIdx.x; i < ncap; i += 256) idxs[i] = src_csr[ebeg + i];
    __syncthreads();

    int g = g0 + (threadIdx.x >> 4);
    if (g >= nN) return;
    int f8 = threadIdx.x & 15;
    float acc[8];
    int gb = row_ptr[g], ge = row_ptr[g + 1];
    if (ge - ebeg <= ncap)
        gather_pipe16((const float4*)HWS2, idxs, gb - ebeg, ge - ebeg, g, f8, acc);
    else
        gather_pipe16((const float4*)HWS2, src_csr, gb, ge, g, f8, acc);
    float dn = dis[g];
    float bv[8], w3[8];
    *(float4*)&bv[0] = ((const float4*)bias)[f8 * 2];
    *(float4*)&bv[4] = ((const float4*)bias)[f8 * 2 + 1];
    *(float4*)&w3[0] = ((const float4*)W3)[f8 * 2];
    *(float4*)&w3[4] = ((const float4*)W3)[f8 * 2 + 1];
    float sum = 0.f;
#pragma unroll
    for (int k = 0; k < 8; ++k)
        sum += fmaxf(acc[k] * dn + bv[k], 0.f) * w3[k];
#pragma unroll
    for (int off = 8; off > 0; off >>= 1) sum += __shfl_down(sum, off, 16);
    if (f8 == 0) hw3s[g] = sum * dn;
}

// scalar pull-aggregation + final relu -> d_out
__global__ __launch_bounds__(256) void k_gather3(const float* __restrict__ hw3s,
                                                 const int* __restrict__ row_ptr,
                                                 const int* __restrict__ src_csr,
                                                 const float* __restrict__ dis,
                                                 const float* __restrict__ b3,
                                                 float* __restrict__ out, int nN) {
    int i = blockIdx.x * 256 + threadIdx.x;
    if (i >= nN) return;
    float acc = hw3s[i];
    int beg = row_ptr[i], end = row_ptr[i + 1];
    for (int e = beg; e < end; ++e) acc += hw3s[src_csr[e]];
    out[i] = fmaxf(acc * dis[i] + b3[0], 0.f);
}

extern "C" void kernel_launch(void* const* d_in, const int* in_sizes, int n_in,
                              void* d_out, int out_size, void* d_ws, size_t ws_size,
                              hipStream_t stream) {
    const float* x  = (const float*)d_in[0];
    const int*   ei = (const int*)d_in[1];
    const float* W1 = (const float*)d_in[2];
    const float* b1 = (const float*)d_in[3];
    const float* W2 = (const float*)d_in[4];
    const float* b2 = (const float*)d_in[5];
    const float* W3 = (const float*)d_in[6];
    const float* b3 = (const float*)d_in[7];

    const int nN = in_sizes[0] / 128;
    const int nE = in_sizes[1] / 2;
    const int* src = ei;
    const int* dst = ei + nE;

    const int nB = (nN + 255) / 256;   // scan blocks (<=256)

    // workspace layout
    char* p = (char*)d_ws;
    int*    cnt8     = (int*)p;           p += (size_t)nN * 8 * 4;
    int*    base8    = (int*)p;           p += (size_t)nN * 8 * 4;
    int*    excl     = (int*)p;           p += (size_t)nN * 4;
    int*    blk_sum  = (int*)p;           p += (size_t)(nB + 1) * 4;
    int*    row_ptr  = (int*)p;           p += (size_t)(nN + 1) * 4;
    int*    rank     = (int*)p;           p += (size_t)nE * 4;
    int*    src_csr  = (int*)p;           p += (size_t)nE * 4;
    float*  dis      = (float*)p;         p += (size_t)nN * 4;
    float*  hw3s     = (float*)p;         p += (size_t)nN * 4;
    p = (char*)(((uintptr_t)p + 255) & ~(uintptr_t)255);
    __half* Wt1      = (__half*)p;        p += (size_t)128 * 128 * 2;
    __half* Wt2      = (__half*)p;        p += (size_t)128 * 128 * 2;
    __half* bufA     = (__half*)p;        p += (size_t)nN * 128 * 2;  // HWS1
    p = (char*)(((uintptr_t)p + 255) & ~(uintptr_t)255);
    __half* bufB     = (__half*)p;        p += (size_t)nN * 128 * 2;  // HWS2

    const int BE  = (nE + 255) / 256;            // 2344
    const int BN  = (nN + 255) / 256;            // 196
    const int BG  = (nN + 63) / 64;              // 782
    const int BGV = (nN + 15) / 16;              // 3125

    // --- CSR build + norms + weight cast (banked count) ---
    hipMemsetAsync(cnt8, 0, (size_t)nN * 8 * sizeof(int), stream);
    k_count_wcast<<<BE + 64, 256, 0, stream>>>(dst, cnt8, rank, nE, BE, nN,
                                               W1, W2, Wt1, Wt2);
    k_scan_blk<<<nB, 256, 0, stream>>>(cnt8, dis, excl, blk_sum, nN);
    k_scan_add<<<nB, 256, 0, stream>>>(excl, blk_sum, cnt8, row_ptr, base8, nN, nB);

    // --- layer-1 GEMM (blocks [0,BG)) overlapped with atomic-free binning ---
    k_gemm_bin<<<BG + BE, 256, 0, stream>>>(x, Wt1, dis, bufA, nN, BG,
                                            src, dst, rank, base8, src_csr, nE);

    // --- fused layer-1 gather + layer-2 GEMM: HWS1 -> HWS2 (512 thr) ---
    k_gather_gemm<<<BG, 512, 0, stream>>>(bufA, row_ptr, src_csr, dis, b1, Wt2,
                                          bufB, nN);

    // --- fused layer-2 gather + layer-3 gemv: HWS2 -> hw3s ---
    k_gather_gemv<<<BGV, 256, 0, stream>>>(bufB, row_ptr, src_csr, dis, b2, W3,
                                           hw3s, nN);

    // --- layer-3 scalar gather -> d_out ---
    k_gather3<<<BN, 256, 0, stream>>>(hw3s, row_ptr, src_csr, dis, b3,
                                      (float*)d_out, nN);
}